// Round 1
// 2001.096 us; speedup vs baseline: 1.1161x; 1.1161x over previous
//
#include <hip/hip_runtime.h>
#include <cstdint>
#include <cstddef>

typedef unsigned short u16;
typedef __attribute__((ext_vector_type(8))) __bf16 bf16x8;
typedef __attribute__((ext_vector_type(8))) unsigned short u16x8;
typedef __attribute__((ext_vector_type(4))) float f32x4;

// ---------- helpers ----------
__device__ __forceinline__ float bf2f(u16 u) {
    return __uint_as_float(((unsigned)u) << 16);
}
__device__ __forceinline__ u16 f2bf(float f) {
    unsigned u = __float_as_uint(f);
    unsigned r = (u + 0x7fffu + ((u >> 16) & 1u)) >> 16;
    return (u16)r;
}
// load element i of a tensor that is f32 (flag=1) or bf16 (flag=0)
__device__ __forceinline__ float ldf(const void* p, long long i, int f) {
    return f ? ((const float*)p)[i] : bf2f(((const u16*)p)[i]);
}
__device__ __forceinline__ u16 ldb(const void* p, long long i, int f) {
    return f ? f2bf(((const float*)p)[i]) : ((const u16*)p)[i];
}

// ---------- dtype probe: f32 data has mantissa-junk in the low u16 of each word ----------
__global__ void detect_dtype(const u16* __restrict__ p, int* __restrict__ flag) {
    const int lane = threadIdx.x;  // 64
    int cnt = 0;
    for (int i = lane; i < 1024; i += 64) {
        const unsigned e = (p[2 * i] >> 7) & 0xFFu;   // exponent field of low-half u16
        cnt += (e >= 117u && e <= 133u) ? 1 : 0;      // N(0,1) bf16 lands here ~97%
    }
#pragma unroll
    for (int d = 32; d; d >>= 1) cnt += __shfl_xor(cnt, d);
    if (lane == 0) *flag = (cnt < 512) ? 1 : 0;       // 1 => inputs are f32
}

// ---------- transpose+convert: dst[n][k] = bf16(src[k][n]) ----------
__global__ void transpose_cv(const void* __restrict__ src, u16* __restrict__ dst,
                             int K, int N, const int* __restrict__ flag)
{
    __shared__ u16 tile[32][33];
    const int f = *flag;
    const int bx = blockIdx.x;  // over N/32
    const int by = blockIdx.y;  // over K/32
    const int tx = threadIdx.x; // 32
    const int ty = threadIdx.y; // 8
#pragma unroll
    for (int j = 0; j < 4; ++j) {
        const long long idx = (long long)(by * 32 + ty + j * 8) * N + bx * 32 + tx;
        tile[ty + j * 8][tx] = ldb(src, idx, f);
    }
    __syncthreads();
#pragma unroll
    for (int j = 0; j < 4; ++j)
        dst[(long long)(bx * 32 + ty + j * 8) * K + by * 32 + tx] = tile[tx][ty + j * 8];
}

// ---------- bias/vector prep: bias1[6144]={0,b_sub,b_obj}, bias2[4096]={b_a1,b_box} ----------
__global__ void build_bias_cv(const void* b_sub, const void* b_obj,
                              const void* b_a1, const void* b_box,
                              const void* b_a2, const void* Wa2,
                              u16* __restrict__ bias1, u16* __restrict__ bias2,
                              u16* __restrict__ wa2_bf, float* __restrict__ ba2f,
                              const int* __restrict__ flag)
{
    const int f = *flag;
    const int i = blockIdx.x * 256 + threadIdx.x;  // 0..6143
    if (i < 2048) {
        bias1[i] = 0;
        bias2[i] = ldb(b_a1, i, f);
        wa2_bf[i] = ldb(Wa2, i, f);
    } else if (i < 4096) {
        bias1[i] = ldb(b_sub, i - 2048, f);
        bias2[i] = ldb(b_box, i - 2048, f);
    } else {
        bias1[i] = ldb(b_obj, i - 4096, f);
    }
    if (i == 0) ba2f[0] = ldf(b_a2, 0, f);
}

// ---------- GEMM: C[M][N] = A[M][K] * Bt[N][K]^T + bias[N] ----------
// A is f32 or bf16 (flag); Bt/bias/C bf16; fp32 accum. 128x128 tile, BK=64,
// 256 thr (4 waves), wave = 64x64 via 4x4 mfma_f32_16x16x32_bf16.
// M%128==0, N%128==0, K%64==0.
// LDS layout: per 128-row x 64-u16 tile, each 128B row is split into eight 16B
// slots; physical slot = logical slot ^ (row&7)  [T2-style XOR swizzle].
// This spreads the 16-lane quarter-wave fragment reads (which otherwise all
// land in one bank quad: stride 128B = 32 dwords) across all 32 banks.
__global__ __launch_bounds__(256) void gemm_cv(
    const void* __restrict__ A, const u16* __restrict__ Bt,
    const u16* __restrict__ bias, u16* __restrict__ C,
    int M, int N, int K, const int* __restrict__ flag)
{
    __shared__ __attribute__((aligned(16))) u16 As[128 * 64];
    __shared__ __attribute__((aligned(16))) u16 Bs[128 * 64];

    const int tid  = threadIdx.x;
    const int wave = tid >> 6, lane = tid & 63;
    const int bm = blockIdx.y, bn = blockIdx.x;
    const int wr = wave >> 1, wc = wave & 1;
    const int f = *flag;

    // staging: thread covers rows srow + j*32 (j=0..3), 8-elem chunk scol
    const int srow = tid >> 3;   // 0..31
    const int scol = tid & 7;    // 0..7
    const long long aRow0 = (long long)(bm * 128 + srow);
    const long long bRow0 = (long long)(bn * 128 + srow);
    const float* Af = (const float*)A;
    const u16*   Ah = (const u16*)A;
    // swizzled 16B slot (row&7 is invariant under the +32-row j steps)
    const int wslot = scol ^ (srow & 7);
    u16* aS = As + srow * 64 + wslot * 8;
    u16* bS = Bs + srow * 64 + wslot * 8;

    f32x4 acc[4][4];
#pragma unroll
    for (int i = 0; i < 4; ++i)
#pragma unroll
        for (int j = 0; j < 4; ++j) acc[i][j] = (f32x4){0.f, 0.f, 0.f, 0.f};

    // fragment addressing: A-op A[m=lane&15][k=quad*8+j]; B-op symmetric (Bt rows)
    const int m_lane = lane & 15;
    const int quad   = lane >> 4;
    const int r3     = m_lane & 7;              // row&7 of every row this lane reads
    const char* aRd = (const char*)As + (wr * 64 + m_lane) * 128;
    const char* bRd = (const char*)Bs + (wc * 64 + m_lane) * 128;

    const int nk = K >> 6;
    for (int kt = 0; kt < nk; ++kt) {
        const long long kofs = (long long)kt * 64 + scol * 8;
        u16x8 av[4], bv[4];
#pragma unroll
        for (int j = 0; j < 4; ++j)
            bv[j] = *(const u16x8*)(Bt + (bRow0 + j * 32) * K + kofs);
        if (f) {
#pragma unroll
            for (int j = 0; j < 4; ++j) {
                const float* pa = Af + (aRow0 + j * 32) * K + kofs;
                const f32x4 x = *(const f32x4*)pa;
                const f32x4 y = *(const f32x4*)(pa + 4);
                unsigned p0, p1, p2, p3;  // packed RNE f32->bf16, 2 elems/instr
                asm("v_cvt_pk_bf16_f32 %0, %1, %2" : "=v"(p0) : "v"(x[0]), "v"(x[1]));
                asm("v_cvt_pk_bf16_f32 %0, %1, %2" : "=v"(p1) : "v"(x[2]), "v"(x[3]));
                asm("v_cvt_pk_bf16_f32 %0, %1, %2" : "=v"(p2) : "v"(y[0]), "v"(y[1]));
                asm("v_cvt_pk_bf16_f32 %0, %1, %2" : "=v"(p3) : "v"(y[2]), "v"(y[3]));
                unsigned* avp = (unsigned*)&av[j];
                avp[0] = p0; avp[1] = p1; avp[2] = p2; avp[3] = p3;
            }
        } else {
#pragma unroll
            for (int j = 0; j < 4; ++j)
                av[j] = *(const u16x8*)(Ah + (aRow0 + j * 32) * K + kofs);
        }
        __syncthreads();   // prior tile's reads done
#pragma unroll
        for (int j = 0; j < 4; ++j) {
            *(u16x8*)(aS + j * 2048) = av[j];
            *(u16x8*)(bS + j * 2048) = bv[j];
        }
        __syncthreads();   // staging visible
#pragma unroll
        for (int ks = 0; ks < 2; ++ks) {
            bf16x8 af[4], bfv[4];
            const int c0 = (((ks << 2) | quad) ^ r3) << 4;  // swizzled 16B slot
#pragma unroll
            for (int i = 0; i < 4; ++i) af[i]  = *(const bf16x8*)(aRd + i * 2048 + c0);
#pragma unroll
            for (int i = 0; i < 4; ++i) bfv[i] = *(const bf16x8*)(bRd + i * 2048 + c0);
#pragma unroll
            for (int mi = 0; mi < 4; ++mi)
#pragma unroll
                for (int ni = 0; ni < 4; ++ni)
                    acc[mi][ni] = __builtin_amdgcn_mfma_f32_16x16x32_bf16(
                        af[mi], bfv[ni], acc[mi][ni], 0, 0, 0);
        }
    }

    // epilogue: C/D layout col=lane&15, row=quad*4+reg  [measured m89/m91]
#pragma unroll
    for (int ni = 0; ni < 4; ++ni) {
        const int col = bn * 128 + wc * 64 + ni * 16 + m_lane;
        const float bv2 = bf2f(bias[col]);
#pragma unroll
        for (int mi = 0; mi < 4; ++mi) {
            const int row0 = bm * 128 + wr * 64 + mi * 16 + quad * 4;
#pragma unroll
            for (int r = 0; r < 4; ++r)
                C[(long long)(row0 + r) * N + col] = f2bf(acc[mi][ni][r] + bv2);
        }
    }
}

// ---------- per-edge logits: Wa2 . relu(rel_att[e] + box_att[node]) + b_a2 ----------
__global__ __launch_bounds__(256) void edge_logits(
    const u16* __restrict__ G1, const u16* __restrict__ G2,
    const int* __restrict__ sub, const int* __restrict__ obj,
    const u16* __restrict__ Wa2, const float* __restrict__ ba2f,
    float* __restrict__ logit_s, float* __restrict__ logit_o)
{
    const int e = blockIdx.x;
    const int t = threadIdx.x;
    const int se = sub[e], oe = obj[e];
    const u16x8 r8 = *(const u16x8*)(G1 + (long long)e * 6144 + t * 8);
    const u16x8 s8 = *(const u16x8*)(G2 + (long long)se * 4096 + t * 8);
    const u16x8 o8 = *(const u16x8*)(G2 + (long long)oe * 4096 + t * 8);
    const u16x8 w8 = *(const u16x8*)(Wa2 + t * 8);
    float aS = 0.f, aO = 0.f;
#pragma unroll
    for (int j = 0; j < 8; ++j) {
        const float rv = bf2f(r8[j]);
        const float wv = bf2f(w8[j]);
        aS += fmaxf(rv + bf2f(s8[j]), 0.f) * wv;
        aO += fmaxf(rv + bf2f(o8[j]), 0.f) * wv;
    }
#pragma unroll
    for (int d = 32; d; d >>= 1) { aS += __shfl_down(aS, d); aO += __shfl_down(aO, d); }
    __shared__ float rs[4], ro[4];
    const int lane = t & 63, wv_ = t >> 6;
    if (lane == 0) { rs[wv_] = aS; ro[wv_] = aO; }
    __syncthreads();
    if (t == 0) {
        const float b = ba2f[0];
        logit_s[e] = rs[0] + rs[1] + rs[2] + rs[3] + b;
        logit_o[e] = ro[0] + ro[1] + ro[2] + ro[3] + b;
    }
}

// ---------- CSR build ----------
__global__ void edge_count(const int* __restrict__ sub, const int* __restrict__ obj,
                           int* __restrict__ cnt_s, int* __restrict__ cnt_o, int E)
{
    const int e = blockIdx.x * 256 + threadIdx.x;
    if (e < E) { atomicAdd(&cnt_s[sub[e]], 1); atomicAdd(&cnt_o[obj[e]], 1); }
}

__global__ void scan_4096x2(const int* __restrict__ cnt_s, const int* __restrict__ cnt_o,
                            int* __restrict__ off_s, int* __restrict__ cur_s,
                            int* __restrict__ off_o, int* __restrict__ cur_o)
{
    __shared__ int buf[1024];
    const int t = threadIdx.x;
    const int* cnt = cnt_s; int* off = off_s; int* cur = cur_s;
    for (int which = 0; which < 2; ++which) {
        const int v0 = cnt[t * 4], v1 = cnt[t * 4 + 1], v2 = cnt[t * 4 + 2], v3 = cnt[t * 4 + 3];
        const int s = v0 + v1 + v2 + v3;
        buf[t] = s;
        __syncthreads();
        for (int d = 1; d < 1024; d <<= 1) {
            const int x = (t >= d) ? buf[t - d] : 0;
            __syncthreads();
            buf[t] += x;
            __syncthreads();
        }
        const int excl = buf[t] - s;
        off[t * 4]     = excl;                cur[t * 4]     = excl;
        off[t * 4 + 1] = excl + v0;           cur[t * 4 + 1] = excl + v0;
        off[t * 4 + 2] = excl + v0 + v1;      cur[t * 4 + 2] = excl + v0 + v1;
        off[t * 4 + 3] = excl + v0 + v1 + v2; cur[t * 4 + 3] = excl + v0 + v1 + v2;
        if (t == 1023) off[4096] = buf[1023];
        __syncthreads();
        cnt = cnt_o; off = off_o; cur = cur_o;
    }
}

__global__ void scatter_edges(const int* __restrict__ sub, const int* __restrict__ obj,
                              int* __restrict__ cur_s, int* __restrict__ cur_o,
                              int* __restrict__ list_s, int* __restrict__ list_o, int E)
{
    const int e = blockIdx.x * 256 + threadIdx.x;
    if (e < E) {
        int p = atomicAdd(&cur_s[sub[e]], 1); list_s[p] = e;
        p = atomicAdd(&cur_o[obj[e]], 1);     list_o[p] = e;
    }
}

// ---------- segment softmax: one wave per node ----------
__global__ __launch_bounds__(256) void seg_softmax(
    const float* __restrict__ logit, const int* __restrict__ off,
    const int* __restrict__ list, float* __restrict__ alpha)
{
    const int node = blockIdx.x * 4 + (threadIdx.x >> 6);
    const int lane = threadIdx.x & 63;
    const int s = off[node], t = off[node + 1];
    float m = -3.4e38f;
    for (int i = s + lane; i < t; i += 64) m = fmaxf(m, logit[list[i]]);
#pragma unroll
    for (int d = 32; d; d >>= 1) m = fmaxf(m, __shfl_xor(m, d));
    float sum = 0.f;
    for (int i = s + lane; i < t; i += 64) {
        const float ev = expf(logit[list[i]] - m);
        alpha[list[i]] = ev;
        sum += ev;
    }
#pragma unroll
    for (int d = 32; d; d >>= 1) sum += __shfl_xor(sum, d);
    const float inv = 1.f / (sum + 1e-9f);
    for (int i = s + lane; i < t; i += 64) alpha[list[i]] *= inv;
}

// ---------- aggregate + final relu: one block per node; dual-dtype store ----------
__global__ __launch_bounds__(256) void aggregate_final(
    const u16* __restrict__ G1, const u16* __restrict__ G2,
    const int* __restrict__ off_s, const int* __restrict__ list_s, const float* __restrict__ alpha_s,
    const int* __restrict__ off_o, const int* __restrict__ list_o, const float* __restrict__ alpha_o,
    void* __restrict__ out, const int* __restrict__ flag)
{
    const int n = blockIdx.x;
    const int t = threadIdx.x;
    const int d0 = t * 8;
    const int f = *flag;
    float acc[8] = {0, 0, 0, 0, 0, 0, 0, 0};
    int s0 = off_s[n], s1 = off_s[n + 1];
    for (int i = s0; i < s1; ++i) {
        const int e = list_s[i];
        const float a = alpha_s[e];
        const u16x8 v = *(const u16x8*)(G1 + (long long)e * 6144 + 2048 + d0);
#pragma unroll
        for (int j = 0; j < 8; ++j) acc[j] += a * bf2f(v[j]);
    }
    s0 = off_o[n]; s1 = off_o[n + 1];
    for (int i = s0; i < s1; ++i) {
        const int e = list_o[i];
        const float a = alpha_o[e];
        const u16x8 v = *(const u16x8*)(G1 + (long long)e * 6144 + 4096 + d0);
#pragma unroll
        for (int j = 0; j < 8; ++j) acc[j] += a * bf2f(v[j]);
    }
    const u16x8 bl = *(const u16x8*)(G2 + (long long)n * 4096 + 2048 + d0);
    float r[8];
#pragma unroll
    for (int j = 0; j < 8; ++j) r[j] = fmaxf(bf2f(bl[j]) + acc[j], 0.f);
    if (f) {
        float* of = (float*)out + (long long)n * 2048 + d0;
        *(f32x4*)of       = (f32x4){r[0], r[1], r[2], r[3]};
        *(f32x4*)(of + 4) = (f32x4){r[4], r[5], r[6], r[7]};
    } else {
        u16x8 o;
#pragma unroll
        for (int j = 0; j < 8; ++j) o[j] = f2bf(r[j]);
        *(u16x8*)((u16*)out + (long long)n * 2048 + d0) = o;
    }
}

// ---------- launch ----------
extern "C" void kernel_launch(void* const* d_in, const int* in_sizes, int n_in,
                              void* d_out, int out_size, void* d_ws, size_t ws_size,
                              hipStream_t stream)
{
    (void)in_sizes; (void)n_in; (void)out_size; (void)ws_size;
    const void* box    = d_in[0];   // [4096][2048]
    const void* rel    = d_in[1];   // [32768][2432]
    const int*  sub    = (const int*)d_in[2];
    const int*  obj    = (const int*)d_in[3];
    const void* W_box  = d_in[4];   // [2048][2048]
    const void* b_box  = d_in[5];
    const void* W_sub  = d_in[6];   // [2432][2048]
    const void* b_sub  = d_in[7];
    const void* W_obj  = d_in[8];   // [2432][2048]
    const void* b_obj  = d_in[9];
    const void* Wa_box = d_in[10];  // [2048][2048]
    const void* Wa_rel = d_in[11];  // [2432][2048]
    const void* b_a1   = d_in[12];
    const void* Wa2    = d_in[13];  // [2048]
    const void* b_a2   = d_in[14];  // [1]

    char* p = (char*)d_ws;
    auto alloc = [&](long long bytes) {
        char* q = p; p += (bytes + 255) & ~255LL; return q;
    };
    int* flag      = (int*)alloc(4);
    float* ba2f    = (float*)alloc(4);
    u16* wa2_bf    = (u16*)alloc(2048 * 2);
    u16* bias1     = (u16*)alloc(6144 * 2);
    u16* bias2     = (u16*)alloc(4096 * 2);
    u16* Bt1       = (u16*)alloc(6144LL * 2432 * 2);   // (Wa_rel|W_sub|W_obj)^T
    u16* Bt2       = (u16*)alloc(4096LL * 2048 * 2);   // (Wa_box|W_box)^T
    u16* G1        = (u16*)alloc(32768LL * 6144 * 2);  // [E][rel_att|msg_sub|msg_obj]
    u16* G2        = (u16*)alloc(4096LL * 4096 * 2);   // [N][box_att+b_a1|box_lin+b_box]
    float* logit_s = (float*)alloc(32768 * 4);
    float* logit_o = (float*)alloc(32768 * 4);
    float* alpha_s = (float*)alloc(32768 * 4);
    float* alpha_o = (float*)alloc(32768 * 4);
    int* cnt       = (int*)alloc(2 * 4096 * 4);
    int* cnt_s = cnt, *cnt_o = cnt + 4096;
    int* off_s     = (int*)alloc(4112 * 4);
    int* off_o     = (int*)alloc(4112 * 4);
    int* cur_s     = (int*)alloc(4096 * 4);
    int* cur_o     = (int*)alloc(4096 * 4);
    int* list_s    = (int*)alloc(32768 * 4);
    int* list_o    = (int*)alloc(32768 * 4);
    // high-water ~484 MB (< ~503 MB demonstrated safe in R1)

    detect_dtype<<<1, 64, 0, stream>>>((const u16*)box, flag);

    const dim3 tb(32, 8);
    transpose_cv<<<dim3(64, 76), tb, 0, stream>>>(Wa_rel, Bt1, 2432, 2048, flag);
    transpose_cv<<<dim3(64, 76), tb, 0, stream>>>(W_sub, Bt1 + 2048LL * 2432, 2432, 2048, flag);
    transpose_cv<<<dim3(64, 76), tb, 0, stream>>>(W_obj, Bt1 + 4096LL * 2432, 2432, 2048, flag);
    transpose_cv<<<dim3(64, 64), tb, 0, stream>>>(Wa_box, Bt2, 2048, 2048, flag);
    transpose_cv<<<dim3(64, 64), tb, 0, stream>>>(W_box, Bt2 + 2048LL * 2048, 2048, 2048, flag);
    build_bias_cv<<<24, 256, 0, stream>>>(b_sub, b_obj, b_a1, b_box, b_a2, Wa2,
                                          bias1, bias2, wa2_bf, ba2f, flag);

    gemm_cv<<<dim3(48, 256), 256, 0, stream>>>(rel, Bt1, bias1, G1, 32768, 6144, 2432, flag);
    gemm_cv<<<dim3(32, 32), 256, 0, stream>>>(box, Bt2, bias2, G2, 4096, 4096, 2048, flag);

    edge_logits<<<32768, 256, 0, stream>>>(G1, G2, sub, obj, wa2_bf, ba2f, logit_s, logit_o);

    hipMemsetAsync(cnt, 0, 2 * 4096 * sizeof(int), stream);
    edge_count<<<128, 256, 0, stream>>>(sub, obj, cnt_s, cnt_o, 32768);
    scan_4096x2<<<1, 1024, 0, stream>>>(cnt_s, cnt_o, off_s, cur_s, off_o, cur_o);
    scatter_edges<<<128, 256, 0, stream>>>(sub, obj, cur_s, cur_o, list_s, list_o, 32768);

    seg_softmax<<<1024, 256, 0, stream>>>(logit_s, off_s, list_s, alpha_s);
    seg_softmax<<<1024, 256, 0, stream>>>(logit_o, off_o, list_o, alpha_o);

    aggregate_final<<<4096, 256, 0, stream>>>(G1, G2, off_s, list_s, alpha_s,
                                              off_o, list_o, alpha_o, d_out, flag);
}